// Round 1
// baseline (3797.123 us; speedup 1.0000x reference)
//
#include <hip/hip_runtime.h>
#include <math.h>

#define NN 100000
#define NE 1600000

__device__ __forceinline__ void atomicMaxF(float* addr, float val) {
    if (val >= 0.0f) atomicMax((int*)addr, __float_as_int(val));
    else             atomicMin((unsigned int*)addr, __float_as_uint(val));
}

__device__ __forceinline__ float leaky02(float v) {
    return v > 0.0f ? v : 0.2f * v;
}

// ---------------- Layer kernels (H=4, D=16, F=64) ----------------

// GEMM z = x@W, attention coeffs el/er, init m/den/acc.
// block=256 (4 waves), 16 nodes/block, grid = NN/16 = 6250
__global__ __launch_bounds__(256) void k_node_prep(
    const float* __restrict__ xin,  // [N,64]
    const float* __restrict__ W,    // [64,64] row-major [k][c]
    const float* __restrict__ al,   // [64] flat (h*16+d)
    const float* __restrict__ ar,   // [64]
    float* __restrict__ z,          // [N,64]
    float* __restrict__ el,         // [N,4]
    float* __restrict__ er,         // [N,4]
    float* __restrict__ m,          // [N,4]
    float* __restrict__ den,        // [N,4]
    float* __restrict__ acc)        // [N,64]
{
    __shared__ float Ws[64 * 64];
    __shared__ float xs[16][64];
    const int t = threadIdx.x;
    const int nodeBase = blockIdx.x * 16;

    #pragma unroll
    for (int i = 0; i < 16; ++i) Ws[t + 256 * i] = W[t + 256 * i];
    #pragma unroll
    for (int i = 0; i < 4; ++i) {
        int idx = t + 256 * i;              // node*64 + k
        xs[idx >> 6][idx & 63] = xin[(size_t)(nodeBase + (idx >> 6)) * 64 + (idx & 63)];
    }
    __syncthreads();

    const int col = t & 63;
    const int ng  = t >> 6;                  // wave id, 4 nodes per wave
    const float a_l = al[col], a_r = ar[col];

    float zacc[4] = {0.f, 0.f, 0.f, 0.f};
    #pragma unroll
    for (int k = 0; k < 64; ++k) {
        float w = Ws[k * 64 + col];
        #pragma unroll
        for (int i = 0; i < 4; ++i) zacc[i] += xs[ng * 4 + i][k] * w;
    }

    #pragma unroll
    for (int i = 0; i < 4; ++i) {
        const int n = nodeBase + ng * 4 + i;
        z[(size_t)n * 64 + col]   = zacc[i];
        acc[(size_t)n * 64 + col] = 0.f;
        float pl = zacc[i] * a_l, pr = zacc[i] * a_r;
        #pragma unroll
        for (int off = 8; off > 0; off >>= 1) {
            pl += __shfl_xor(pl, off, 16);
            pr += __shfl_xor(pr, off, 16);
        }
        if ((col & 15) == 0) {
            const int h = col >> 4;
            el[n * 4 + h]  = pl;
            er[n * 4 + h]  = pr;
            m[n * 4 + h]   = -__builtin_inff();
            den[n * 4 + h] = 0.f;
        }
    }
}

// Pass 1 over edges: segment max of leaky(el[src]+er[dst]) into m[dst].
__global__ __launch_bounds__(256) void k_edge_max(
    const int* __restrict__ src, const int* __restrict__ dst,
    const float* __restrict__ el, const float* __restrict__ er,
    float* __restrict__ m)
{
    const int e = blockIdx.x * 256 + threadIdx.x;
    if (e >= NE) return;
    const int s = src[e], d = dst[e];
    const float4 ev = *(const float4*)(el + (size_t)s * 4);
    const float4 rv = *(const float4*)(er + (size_t)d * 4);
    atomicMaxF(&m[d * 4 + 0], leaky02(ev.x + rv.x));
    atomicMaxF(&m[d * 4 + 1], leaky02(ev.y + rv.y));
    atomicMaxF(&m[d * 4 + 2], leaky02(ev.z + rv.z));
    atomicMaxF(&m[d * 4 + 3], leaky02(ev.w + rv.w));
}

// Pass 2 over edges: ex = exp(e - m[dst]); den[dst]+=ex; acc[dst]+=ex*z[src].
// 16 lanes per edge (lane handles a float4 of the 64-dim row), 16 edges/block.
// grid = NE/16 = 100000
__global__ __launch_bounds__(256) void k_edge_agg(
    const int* __restrict__ src, const int* __restrict__ dst,
    const float* __restrict__ el, const float* __restrict__ er,
    const float* __restrict__ m, const float* __restrict__ z,
    float* __restrict__ den, float* __restrict__ acc)
{
    const int t = threadIdx.x;
    const int lane = t & 15;
    const int e = blockIdx.x * 16 + (t >> 4);
    const int s = src[e], d = dst[e];
    const int h = lane >> 2;                       // head for this float4
    float v = leaky02(el[s * 4 + h] + er[d * 4 + h]);
    const float ex = expf(v - m[d * 4 + h]);
    if ((lane & 3) == 0) atomicAdd(&den[d * 4 + h], ex);
    const float4 zv = *(const float4*)(z + (size_t)s * 64 + lane * 4);
    float* ap = acc + (size_t)d * 64 + lane * 4;
    atomicAdd(ap + 0, ex * zv.x);
    atomicAdd(ap + 1, ex * zv.y);
    atomicAdd(ap + 2, ex * zv.z);
    atomicAdd(ap + 3, ex * zv.w);
}

// Epilogue: xout = [relu](acc/max(den,1e-9) + b)
__global__ __launch_bounds__(256) void k_node_finish(
    const float* __restrict__ acc, const float* __restrict__ den,
    const float* __restrict__ b, float* __restrict__ xout, int relu)
{
    const int idx = blockIdx.x * 256 + threadIdx.x;   // node*64 + col
    if (idx >= NN * 64) return;
    const int n = idx >> 6, col = idx & 63, h = col >> 4;
    float v = acc[idx] / fmaxf(den[n * 4 + h], 1e-9f) + b[col];
    if (relu) v = fmaxf(v, 0.f);
    xout[idx] = v;
}

// ---------------- Output layer (H=1, D=1) ----------------

// zo = x @ Wo (64->1). 16 lanes/node, grid = NN/16 = 6250
__global__ __launch_bounds__(256) void k_node_prep_o(
    const float* __restrict__ xin, const float* __restrict__ Wo,
    float* __restrict__ zo, float* __restrict__ mo,
    float* __restrict__ deno, float* __restrict__ acco)
{
    __shared__ float Ws[64];
    const int t = threadIdx.x;
    if (t < 64) Ws[t] = Wo[t];
    __syncthreads();
    const int lane = t & 15;
    const int n = blockIdx.x * 16 + (t >> 4);
    const float4 xv = *(const float4*)(xin + (size_t)n * 64 + lane * 4);
    const float4 wv = *(const float4*)(Ws + lane * 4);
    float p = xv.x * wv.x + xv.y * wv.y + xv.z * wv.z + xv.w * wv.w;
    #pragma unroll
    for (int off = 8; off > 0; off >>= 1) p += __shfl_xor(p, off, 16);
    if (lane == 0) { zo[n] = p; mo[n] = -__builtin_inff(); deno[n] = 0.f; acco[n] = 0.f; }
}

__global__ __launch_bounds__(256) void k_edge_max_o(
    const int* __restrict__ src, const int* __restrict__ dst,
    const float* __restrict__ zo, const float* __restrict__ alo,
    const float* __restrict__ aro, float* __restrict__ mo)
{
    const int e = blockIdx.x * 256 + threadIdx.x;
    if (e >= NE) return;
    const float v = leaky02(alo[0] * zo[src[e]] + aro[0] * zo[dst[e]]);
    atomicMaxF(&mo[dst[e]], v);
}

__global__ __launch_bounds__(256) void k_edge_agg_o(
    const int* __restrict__ src, const int* __restrict__ dst,
    const float* __restrict__ zo, const float* __restrict__ alo,
    const float* __restrict__ aro, const float* __restrict__ mo,
    float* __restrict__ deno, float* __restrict__ acco)
{
    const int e = blockIdx.x * 256 + threadIdx.x;
    if (e >= NE) return;
    const int s = src[e], d = dst[e];
    const float v = leaky02(alo[0] * zo[s] + aro[0] * zo[d]);
    const float ex = expf(v - mo[d]);
    atomicAdd(&deno[d], ex);
    atomicAdd(&acco[d], ex * zo[s]);
}

__global__ __launch_bounds__(256) void k_out(
    const float* __restrict__ acco, const float* __restrict__ deno,
    const float* __restrict__ bo, float* __restrict__ out)
{
    const int n = blockIdx.x * 256 + threadIdx.x;
    if (n >= NN) return;
    out[n] = acco[n] / fmaxf(deno[n], 1e-9f) + bo[0];
}

// ---------------- Launch ----------------

extern "C" void kernel_launch(void* const* d_in, const int* in_sizes, int n_in,
                              void* d_out, int out_size, void* d_ws, size_t ws_size,
                              hipStream_t stream) {
    const float* feat = (const float*)d_in[0];
    const int*   src  = (const int*)d_in[1];
    const int*   dst  = (const int*)d_in[2];
    const float* W0   = (const float*)d_in[3];
    const float* al0  = (const float*)d_in[4];
    const float* ar0  = (const float*)d_in[5];
    const float* b0   = (const float*)d_in[6];
    const float* W1   = (const float*)d_in[7];
    const float* al1  = (const float*)d_in[8];
    const float* ar1  = (const float*)d_in[9];
    const float* b1   = (const float*)d_in[10];
    const float* Wo   = (const float*)d_in[11];
    const float* alo  = (const float*)d_in[12];
    const float* aro  = (const float*)d_in[13];
    const float* bo   = (const float*)d_in[14];
    float* out = (float*)d_out;

    float* ws  = (float*)d_ws;
    float* z   = ws;                 // [N,64]
    float* acc = z + (size_t)NN * 64; // [N,64]
    float* x   = acc + (size_t)NN * 64; // [N,64] layer features
    float* el  = x + (size_t)NN * 64;   // [N,4]
    float* er  = el + (size_t)NN * 4;
    float* m   = er + (size_t)NN * 4;
    float* den = m + (size_t)NN * 4;
    float* zo  = el;                 // reuse for output layer ([N])

    const int nbNode16 = NN / 16;        // 6250
    const int nbEdge1  = (NE + 255) / 256; // 6250
    const int nbEdge16 = NE / 16;        // 100000
    const int nbNode64 = NN * 64 / 256;  // 25000

    // Layer 0
    k_node_prep<<<nbNode16, 256, 0, stream>>>(feat, W0, al0, ar0, z, el, er, m, den, acc);
    k_edge_max<<<nbEdge1, 256, 0, stream>>>(src, dst, el, er, m);
    k_edge_agg<<<nbEdge16, 256, 0, stream>>>(src, dst, el, er, m, z, den, acc);
    k_node_finish<<<nbNode64, 256, 0, stream>>>(acc, den, b0, x, 1);

    // Layer 1
    k_node_prep<<<nbNode16, 256, 0, stream>>>(x, W1, al1, ar1, z, el, er, m, den, acc);
    k_edge_max<<<nbEdge1, 256, 0, stream>>>(src, dst, el, er, m);
    k_edge_agg<<<nbEdge16, 256, 0, stream>>>(src, dst, el, er, m, z, den, acc);
    k_node_finish<<<nbNode64, 256, 0, stream>>>(acc, den, b1, x, 1);

    // Output layer
    k_node_prep_o<<<nbNode16, 256, 0, stream>>>(x, Wo, zo, m, den, acc);
    k_edge_max_o<<<nbEdge1, 256, 0, stream>>>(src, dst, zo, alo, aro, m);
    k_edge_agg_o<<<nbEdge1, 256, 0, stream>>>(src, dst, zo, alo, aro, m, den, acc);
    k_out<<<(NN + 255) / 256, 256, 0, stream>>>(acc, den, bo, out);
}

// Round 2
// 610.139 us; speedup vs baseline: 6.2234x; 6.2234x over previous
//
#include <hip/hip_runtime.h>
#include <math.h>

#define NN 100000
#define NE 1600000
#define NB 391   // ceil(NN/256)

__device__ __forceinline__ float leaky02(float v) {
    return v > 0.0f ? v : 0.2f * v;
}

// ---------------- CSR build (once per call, reused by all 3 layers) ----------

__global__ __launch_bounds__(256) void k_hist(
    const int* __restrict__ dst, int* __restrict__ cnt)
{
    const int e = blockIdx.x * 256 + threadIdx.x;
    if (e < NE) atomicAdd(&cnt[dst[e]], 1);
}

__global__ __launch_bounds__(256) void k_bsum(
    const int* __restrict__ cnt, int* __restrict__ bsum)
{
    const int i = blockIdx.x * 256 + threadIdx.x;
    int v = (i < NN) ? cnt[i] : 0;
    #pragma unroll
    for (int off = 32; off; off >>= 1) v += __shfl_down(v, off, 64);
    __shared__ int s[4];
    if ((threadIdx.x & 63) == 0) s[threadIdx.x >> 6] = v;
    __syncthreads();
    if (threadIdx.x == 0) bsum[blockIdx.x] = s[0] + s[1] + s[2] + s[3];
}

__global__ __launch_bounds__(512) void k_scanb(
    const int* __restrict__ bsum, int* __restrict__ boff)
{
    __shared__ int s[512];
    const int t = threadIdx.x;
    const int v = (t < NB) ? bsum[t] : 0;
    s[t] = v; __syncthreads();
    for (int off = 1; off < 512; off <<= 1) {
        int u = (t >= off) ? s[t - off] : 0;
        __syncthreads(); s[t] += u; __syncthreads();
    }
    if (t < NB) boff[t] = s[t] - v;   // exclusive
}

__global__ __launch_bounds__(256) void k_scanf(
    const int* __restrict__ cnt, const int* __restrict__ boff,
    int* __restrict__ row_ptr)
{
    __shared__ int s[256];
    const int i = blockIdx.x * 256 + threadIdx.x;
    const int t = threadIdx.x;
    const int c = (i < NN) ? cnt[i] : 0;
    s[t] = c; __syncthreads();
    for (int off = 1; off < 256; off <<= 1) {
        int u = (t >= off) ? s[t - off] : 0;
        __syncthreads(); s[t] += u; __syncthreads();
    }
    if (i < NN)     row_ptr[i]  = boff[blockIdx.x] + s[t] - c;
    if (i == NN - 1) row_ptr[NN] = boff[blockIdx.x] + s[t];
}

__global__ __launch_bounds__(256) void k_scatter(
    const int* __restrict__ src, const int* __restrict__ dst,
    const int* __restrict__ row_ptr, int* __restrict__ fill,
    int* __restrict__ ssrc)
{
    const int e = blockIdx.x * 256 + threadIdx.x;
    if (e >= NE) return;
    const int d = dst[e];
    const int pos = row_ptr[d] + atomicAdd(&fill[d], 1);
    ssrc[pos] = src[e];
}

// ---------------- Layer kernels (H=4, D=16, F=64) ----------------

// GEMM z = x@W + attention coeffs el/er. 16 nodes/block, grid=6250.
__global__ __launch_bounds__(256) void k_node_prep(
    const float* __restrict__ xin,  // [N,64]
    const float* __restrict__ W,    // [64,64]
    const float* __restrict__ al,   // [64]
    const float* __restrict__ ar,   // [64]
    float* __restrict__ z,          // [N,64]
    float* __restrict__ el,         // [N,4]
    float* __restrict__ er)         // [N,4]
{
    __shared__ float Ws[64 * 64];
    __shared__ float xs[16][64];
    const int t = threadIdx.x;
    const int nodeBase = blockIdx.x * 16;

    #pragma unroll
    for (int i = 0; i < 16; ++i) Ws[t + 256 * i] = W[t + 256 * i];
    #pragma unroll
    for (int i = 0; i < 4; ++i) {
        int idx = t + 256 * i;
        xs[idx >> 6][idx & 63] = xin[(size_t)(nodeBase + (idx >> 6)) * 64 + (idx & 63)];
    }
    __syncthreads();

    const int col = t & 63;
    const int ng  = t >> 6;
    const float a_l = al[col], a_r = ar[col];

    float zacc[4] = {0.f, 0.f, 0.f, 0.f};
    #pragma unroll
    for (int k = 0; k < 64; ++k) {
        float w = Ws[k * 64 + col];
        #pragma unroll
        for (int i = 0; i < 4; ++i) zacc[i] += xs[ng * 4 + i][k] * w;
    }

    #pragma unroll
    for (int i = 0; i < 4; ++i) {
        const int n = nodeBase + ng * 4 + i;
        z[(size_t)n * 64 + col] = zacc[i];
        float pl = zacc[i] * a_l, pr = zacc[i] * a_r;
        #pragma unroll
        for (int off = 8; off > 0; off >>= 1) {
            pl += __shfl_xor(pl, off, 16);
            pr += __shfl_xor(pr, off, 16);
        }
        if ((col & 15) == 0) {
            const int h = col >> 4;
            el[n * 4 + h] = pl;
            er[n * 4 + h] = pr;
        }
    }
}

// Fused per-node aggregation: softmax-max, exp-sum, weighted gather-sum,
// normalize + bias + relu. One wave per node, 4 nodes/block, grid=25000.
__global__ __launch_bounds__(256) void k_csr_agg(
    const int* __restrict__ row_ptr, const int* __restrict__ ssrc,
    const float* __restrict__ el, const float* __restrict__ er,
    const float* __restrict__ z, const float* __restrict__ b,
    float* __restrict__ xout, int relu)
{
    const int t = threadIdx.x;
    const int wv = t >> 6, f = t & 63, h = f >> 4, subl = f & 15;
    const int n = blockIdx.x * 4 + wv;
    const int beg = row_ptr[n], end = row_ptr[n + 1];
    const float erh = er[n * 4 + h];

    // phase 1: per-head max over incoming edges (16 lanes per head, strided)
    float mx = -3.4e38f;
    for (int i = beg + subl; i < end; i += 16) {
        const int s = ssrc[i];
        mx = fmaxf(mx, leaky02(el[s * 4 + h] + erh));
    }
    #pragma unroll
    for (int off = 8; off; off >>= 1) mx = fmaxf(mx, __shfl_xor(mx, off, 16));

    // phase 2: accumulate ex and ex*z[src][f] (all 64 lanes walk every edge)
    float accv = 0.f, den = 0.f;
    int i = beg;
    for (; i + 1 < end; i += 2) {
        const int s0 = ssrc[i], s1 = ssrc[i + 1];
        const float z0 = z[(size_t)s0 * 64 + f], z1 = z[(size_t)s1 * 64 + f];
        const float e0 = leaky02(el[s0 * 4 + h] + erh);
        const float e1 = leaky02(el[s1 * 4 + h] + erh);
        const float x0 = __expf(e0 - mx), x1 = __expf(e1 - mx);
        den  += x0 + x1;
        accv += x0 * z0 + x1 * z1;
    }
    if (i < end) {
        const int s0 = ssrc[i];
        const float x0 = __expf(leaky02(el[s0 * 4 + h] + erh) - mx);
        den  += x0;
        accv += x0 * z[(size_t)s0 * 64 + f];
    }

    float v = accv / fmaxf(den, 1e-9f) + b[f];
    if (relu) v = fmaxf(v, 0.f);
    xout[(size_t)n * 64 + f] = v;
}

// ---------------- Output layer (H=1, D=1) ----------------

__global__ __launch_bounds__(256) void k_node_prep_o(
    const float* __restrict__ xin, const float* __restrict__ Wo,
    float* __restrict__ zo)
{
    __shared__ float Ws[64];
    const int t = threadIdx.x;
    if (t < 64) Ws[t] = Wo[t];
    __syncthreads();
    const int lane = t & 15;
    const int n = blockIdx.x * 16 + (t >> 4);
    const float4 xv = *(const float4*)(xin + (size_t)n * 64 + lane * 4);
    const float4 wv = *(const float4*)(Ws + lane * 4);
    float p = xv.x * wv.x + xv.y * wv.y + xv.z * wv.z + xv.w * wv.w;
    #pragma unroll
    for (int off = 8; off > 0; off >>= 1) p += __shfl_xor(p, off, 16);
    if (lane == 0) zo[n] = p;
}

// One thread per node: max pass + accumulate pass, fused epilogue.
__global__ __launch_bounds__(256) void k_csr_agg_o(
    const int* __restrict__ row_ptr, const int* __restrict__ ssrc,
    const float* __restrict__ zo, const float* __restrict__ alo,
    const float* __restrict__ aro, const float* __restrict__ bo,
    float* __restrict__ out)
{
    const int n = blockIdx.x * 256 + threadIdx.x;
    if (n >= NN) return;
    const float a = alo[0];
    const float zr = aro[0] * zo[n];
    const int beg = row_ptr[n], end = row_ptr[n + 1];
    float mx = -3.4e38f;
    for (int i = beg; i < end; ++i)
        mx = fmaxf(mx, leaky02(a * zo[ssrc[i]] + zr));
    float den = 0.f, accv = 0.f;
    for (int i = beg; i < end; ++i) {
        const float zs = zo[ssrc[i]];
        const float ex = __expf(leaky02(a * zs + zr) - mx);
        den += ex; accv += ex * zs;
    }
    out[n] = accv / fmaxf(den, 1e-9f) + bo[0];
}

// ---------------- Launch ----------------

extern "C" void kernel_launch(void* const* d_in, const int* in_sizes, int n_in,
                              void* d_out, int out_size, void* d_ws, size_t ws_size,
                              hipStream_t stream) {
    const float* feat = (const float*)d_in[0];
    const int*   src  = (const int*)d_in[1];
    const int*   dst  = (const int*)d_in[2];
    const float* W0   = (const float*)d_in[3];
    const float* al0  = (const float*)d_in[4];
    const float* ar0  = (const float*)d_in[5];
    const float* b0   = (const float*)d_in[6];
    const float* W1   = (const float*)d_in[7];
    const float* al1  = (const float*)d_in[8];
    const float* ar1  = (const float*)d_in[9];
    const float* b1   = (const float*)d_in[10];
    const float* Wo   = (const float*)d_in[11];
    const float* alo  = (const float*)d_in[12];
    const float* aro  = (const float*)d_in[13];
    const float* bo   = (const float*)d_in[14];
    float* out = (float*)d_out;

    // workspace carve-up (ints first, then floats)
    int* cnt     = (int*)d_ws;                 // [NN]
    int* fill    = cnt + NN;                   // [NN]
    int* bsum    = fill + NN;                  // [NB]
    int* boff    = bsum + NB;                  // [NB]
    int* row_ptr = boff + NB;                  // [NN+1]
    int* ssrc    = row_ptr + (NN + 1);         // [NE]
    float* z  = (float*)(ssrc + NE);           // [NN*64]
    float* xA = z + (size_t)NN * 64;           // [NN*64]
    float* el = xA + (size_t)NN * 64;          // [NN*4]
    float* er = el + (size_t)NN * 4;           // [NN*4]
    float* zo = el;                            // reuse ([NN])

    const int gE  = (NE + 255) / 256;   // 6250
    const int gN16 = NN / 16;           // 6250
    const int gAgg = NN / 4;            // 25000

    // CSR build
    hipMemsetAsync(cnt, 0, 2 * NN * sizeof(int), stream);  // cnt + fill
    k_hist   <<<gE, 256, 0, stream>>>(dst, cnt);
    k_bsum   <<<NB, 256, 0, stream>>>(cnt, bsum);
    k_scanb  <<<1, 512, 0, stream>>>(bsum, boff);
    k_scanf  <<<NB, 256, 0, stream>>>(cnt, boff, row_ptr);
    k_scatter<<<gE, 256, 0, stream>>>(src, dst, row_ptr, fill, ssrc);

    // Layer 0: feat -> xA
    k_node_prep<<<gN16, 256, 0, stream>>>(feat, W0, al0, ar0, z, el, er);
    k_csr_agg  <<<gAgg, 256, 0, stream>>>(row_ptr, ssrc, el, er, z, b0, xA, 1);

    // Layer 1: xA -> xA (xA dead after prep writes z/el/er)
    k_node_prep<<<gN16, 256, 0, stream>>>(xA, W1, al1, ar1, z, el, er);
    k_csr_agg  <<<gAgg, 256, 0, stream>>>(row_ptr, ssrc, el, er, z, b1, xA, 1);

    // Output layer
    k_node_prep_o<<<gN16, 256, 0, stream>>>(xA, Wo, zo);
    k_csr_agg_o  <<<NB, 256, 0, stream>>>(row_ptr, ssrc, zo, alo, aro, bo, out);
}